// Round 2
// baseline (859.961 us; speedup 1.0000x reference)
//
#include <hip/hip_runtime.h>
#include <hip/hip_bf16.h>

#define SEQ   2048
#define DM    1024
#define NH    16
#define DH    64
#define MAXD  128

// dtype modes for kernel operands: 0 = fp32, 1 = bf16, 2 = resolve from flag
#define MODE_F32  0
#define MODE_BF16 1
#define MODE_FLAG 2

__device__ __forceinline__ float ldv(const void* p, size_t i, bool bf) {
    return bf ? __bfloat162float(((const __hip_bfloat16*)p)[i])
              : ((const float*)p)[i];
}
__device__ __forceinline__ void stv(void* p, size_t i, float v, bool bf) {
    if (bf) ((__hip_bfloat16*)p)[i] = __float2bfloat16(v);
    else    ((float*)p)[i] = v;
}
__device__ __forceinline__ bool resolve(int mode, const int* flagp) {
    if (mode == MODE_F32)  return false;
    if (mode == MODE_BF16) return true;
    return *flagp != 0;
}

// ---------------------------------------------------------------------------
// Detect input dtype: sample first 2048 elements of x interpreted as bf16.
// bf16 N(0,1) data -> ~100% in sane range; fp32 data read as bf16 -> ~56%.
// flag = 1 means inputs are bf16.
// ---------------------------------------------------------------------------
__global__ __launch_bounds__(256) void detect_kernel(const void* __restrict__ x,
                                                     int* __restrict__ flagp) {
    __shared__ int cnt[256];
    const int t = threadIdx.x;
    const __hip_bfloat16* xb = (const __hip_bfloat16*)x;
    int c = 0;
#pragma unroll
    for (int i = 0; i < 8; ++i) {
        float a = fabsf(__bfloat162float(xb[t * 8 + i]));
        if (a > 9.5e-7f && a < 1024.f) ++c;   // NaN fails both compares
    }
    cnt[t] = c;
    __syncthreads();
    for (int s = 128; s > 0; s >>= 1) {
        if (t < s) cnt[t] += cnt[t + s];
        __syncthreads();
    }
    if (t == 0) *flagp = (cnt[0] > 1536) ? 1 : 0;   // >75% sane => bf16
}

// ---------------------------------------------------------------------------
// Generic 64x64-tile GEMM, 256 threads, 4x4 micro-tile per thread, fp32 accum.
// A[M,K] row-major, B[K,N] row-major, C[M,N] row-major.
// Operand dtypes resolved at runtime from (mode, flag).
// ---------------------------------------------------------------------------
__global__ __launch_bounds__(256) void gemm64(const void* __restrict__ A,
                                              const void* __restrict__ B,
                                              void* __restrict__ C,
                                              int M, int N, int K,
                                              const int* __restrict__ flagp,
                                              int aMode, int bMode, int cMode) {
    const bool bfA = resolve(aMode, flagp);
    const bool bfB = resolve(bMode, flagp);
    const bool bfC = resolve(cMode, flagp);

    __shared__ float As[64][17];  // [m][k], padded
    __shared__ float Bs[16][65];  // [k][n], padded

    const int t  = threadIdx.x;
    const int tx = t % 16;   // n-group
    const int ty = t / 16;   // m-group
    const int row0 = blockIdx.y * 64;
    const int col0 = blockIdx.x * 64;

    const int ar = t / 16, ac = t % 16;   // A-tile 64x16 load map
    const int br = t / 64, bc = t % 64;   // B-tile 16x64 load map

    float acc[4][4];
#pragma unroll
    for (int i = 0; i < 4; ++i)
#pragma unroll
        for (int j = 0; j < 4; ++j) acc[i][j] = 0.f;

    for (int k0 = 0; k0 < K; k0 += 16) {
#pragma unroll
        for (int p = 0; p < 4; ++p)
            As[ar + p * 16][ac] = ldv(A, (size_t)(row0 + ar + p * 16) * K + k0 + ac, bfA);
#pragma unroll
        for (int p = 0; p < 4; ++p)
            Bs[br + p * 4][bc] = ldv(B, (size_t)(k0 + br + p * 4) * N + col0 + bc, bfB);
        __syncthreads();

#pragma unroll
        for (int kk = 0; kk < 16; ++kk) {
            float a[4], b[4];
#pragma unroll
            for (int i = 0; i < 4; ++i) a[i] = As[ty + i * 16][kk];
#pragma unroll
            for (int j = 0; j < 4; ++j) b[j] = Bs[kk][tx + j * 16];
#pragma unroll
            for (int i = 0; i < 4; ++i)
#pragma unroll
                for (int j = 0; j < 4; ++j) acc[i][j] += a[i] * b[j];
        }
        __syncthreads();
    }

#pragma unroll
    for (int i = 0; i < 4; ++i)
#pragma unroll
        for (int j = 0; j < 4; ++j)
            stv(C, (size_t)(row0 + ty + i * 16) * N + col0 + tx + j * 16, acc[i][j], bfC);
}

// ---------------------------------------------------------------------------
// Flash-style attention with T5 relative-position bias.
// grid = (SEQ/64, NH); block = 256 threads.
// qkv: fp32 [SEQ][3*DM]; attn out: fp32 [SEQ][DM].
// ---------------------------------------------------------------------------
__global__ __launch_bounds__(256) void attn_kernel(const float* __restrict__ qkv,
                                                   const void* __restrict__ rel_bias,
                                                   float* __restrict__ attn,
                                                   const int* __restrict__ flagp) {
    const bool bfBias = (*flagp != 0);

    __shared__ float Qt[64][65];
    __shared__ float Kt[64][65];
    __shared__ float Vt[64][65];
    __shared__ float Sb[64][65];
    __shared__ float biasL[MAXD];
    __shared__ float mrow[64], lrow[64], alphaL[64], mnewL[64];
    __shared__ float pmax[4][64], psum[4][64];

    const int t  = threadIdx.x;
    const int qb = blockIdx.x;   // 0..31
    const int h  = blockIdx.y;   // 0..15
    const int q0 = qb * 64;

    const int tx = t % 16;
    const int ty = t / 16;

    // load Q tile (scaled by 1/sqrt(DH) = 0.125)
    {
        const int c  = t % 64;
        const int r0 = t / 64;  // 0..3
#pragma unroll
        for (int p = 0; p < 16; ++p) {
            const int r = r0 + p * 4;
            Qt[r][c] = qkv[(size_t)(q0 + r) * (3 * DM) + h * DH + c] * 0.125f;
        }
    }
    if (t < MAXD) biasL[t] = ldv(rel_bias, (size_t)t * NH + h, bfBias);
    if (t < 64) { mrow[t] = -1e30f; lrow[t] = 0.f; }

    float acc[4][4];
#pragma unroll
    for (int i = 0; i < 4; ++i)
#pragma unroll
        for (int j = 0; j < 4; ++j) acc[i][j] = 0.f;

    for (int kb = 0; kb < SEQ / 64; ++kb) {
        const int k0 = kb * 64;
        // stage K, V tiles
        {
            const int c  = t % 64;
            const int r0 = t / 64;
#pragma unroll
            for (int p = 0; p < 16; ++p) {
                const int r = r0 + p * 4;
                Kt[r][c] = qkv[(size_t)(k0 + r) * (3 * DM) + DM + h * DH + c];
                Vt[r][c] = qkv[(size_t)(k0 + r) * (3 * DM) + 2 * DM + h * DH + c];
            }
        }
        __syncthreads();

        // Phase A: scores S[q][k] = (q/8)·k + bias
        {
            float s[4][4];
#pragma unroll
            for (int i = 0; i < 4; ++i)
#pragma unroll
                for (int j = 0; j < 4; ++j) s[i][j] = 0.f;
            for (int d = 0; d < DH; ++d) {
                float a[4], b[4];
#pragma unroll
                for (int i = 0; i < 4; ++i) a[i] = Qt[ty + i * 16][d];
#pragma unroll
                for (int j = 0; j < 4; ++j) b[j] = Kt[tx + j * 16][d];
#pragma unroll
                for (int i = 0; i < 4; ++i)
#pragma unroll
                    for (int j = 0; j < 4; ++j) s[i][j] += a[i] * b[j];
            }
#pragma unroll
            for (int i = 0; i < 4; ++i) {
                const int qg = q0 + ty + i * 16;
#pragma unroll
                for (int j = 0; j < 4; ++j) {
                    const int kg  = k0 + tx + j * 16;
                    int rel = kg - qg; if (rel < 0) rel = -rel;
                    if (rel > MAXD - 1) rel = MAXD - 1;
                    Sb[ty + i * 16][tx + j * 16] = s[i][j] + biasL[rel];
                }
            }
        }
        __syncthreads();

        // B1: partial row max
        {
            const int q = t % 64, quarter = t / 64;
            float m = -1e30f;
#pragma unroll
            for (int kk = 0; kk < 16; ++kk) m = fmaxf(m, Sb[q][quarter * 16 + kk]);
            pmax[quarter][q] = m;
        }
        __syncthreads();
        // B2: new row max + alpha
        if (t < 64) {
            const int q = t;
            float mb = fmaxf(fmaxf(pmax[0][q], pmax[1][q]), fmaxf(pmax[2][q], pmax[3][q]));
            float mn = fmaxf(mrow[q], mb);
            alphaL[q] = __expf(mrow[q] - mn);
            mnewL[q]  = mn;
        }
        __syncthreads();
        // B3: exponentiate in place + partial sums
        {
            const int q = t % 64, quarter = t / 64;
            float ps = 0.f;
            const float mn = mnewL[q];
#pragma unroll
            for (int kk = 0; kk < 16; ++kk) {
                const int k = quarter * 16 + kk;
                float p = __expf(Sb[q][k] - mn);
                Sb[q][k] = p;
                ps += p;
            }
            psum[quarter][q] = ps;
        }
        __syncthreads();
        // B4: update l, m
        if (t < 64) {
            const int q = t;
            lrow[q] = lrow[q] * alphaL[q] + psum[0][q] + psum[1][q] + psum[2][q] + psum[3][q];
            mrow[q] = mnewL[q];
        }
        __syncthreads();

        // Phase C: O = O*alpha + P·V
        {
#pragma unroll
            for (int i = 0; i < 4; ++i) {
                const float al = alphaL[ty + i * 16];
#pragma unroll
                for (int j = 0; j < 4; ++j) acc[i][j] *= al;
            }
            for (int k = 0; k < 64; ++k) {
                float p[4], vv[4];
#pragma unroll
                for (int i = 0; i < 4; ++i) p[i] = Sb[ty + i * 16][k];
#pragma unroll
                for (int j = 0; j < 4; ++j) vv[j] = Vt[k][tx + j * 16];
#pragma unroll
                for (int i = 0; i < 4; ++i)
#pragma unroll
                    for (int j = 0; j < 4; ++j) acc[i][j] += p[i] * vv[j];
            }
        }
        __syncthreads();  // before Kt/Vt/Sb are overwritten
    }

    // normalize and store
#pragma unroll
    for (int i = 0; i < 4; ++i) {
        const int q = ty + i * 16;
        const float inv_l = 1.0f / lrow[q];
#pragma unroll
        for (int j = 0; j < 4; ++j) {
            const int d = tx + j * 16;
            attn[(size_t)(q0 + q) * DM + h * DH + d] = acc[i][j] * inv_l;
        }
    }
}

extern "C" void kernel_launch(void* const* d_in, const int* in_sizes, int n_in,
                              void* d_out, int out_size, void* d_ws, size_t ws_size,
                              hipStream_t stream) {
    const void* x        = d_in[0];
    const void* w_qkv    = d_in[1];
    const void* w_out    = d_in[2];
    const void* rel_bias = d_in[3];

    // ws layout: [0..255] flag; then qkv fp32 [SEQ][3*DM]; then attn fp32 [SEQ][DM]
    int*   flagp = (int*)d_ws;
    float* qkv   = (float*)((char*)d_ws + 256);
    float* attn  = (float*)((char*)d_ws + 256 + (size_t)SEQ * 3 * DM * sizeof(float));

    // 0) detect input dtype (bf16 vs fp32)
    detect_kernel<<<1, 256, 0, stream>>>(x, flagp);

    // 1) QKV projection: x @ w_qkv -> qkv (fp32)
    gemm64<<<dim3(3 * DM / 64, SEQ / 64), 256, 0, stream>>>(
        x, w_qkv, qkv, SEQ, 3 * DM, DM, flagp, MODE_FLAG, MODE_FLAG, MODE_F32);

    // 2) attention -> attn (fp32)
    attn_kernel<<<dim3(SEQ / 64, NH), 256, 0, stream>>>(qkv, rel_bias, attn, flagp);

    // 3) output projection: attn @ w_out -> out (dtype follows input dtype)
    gemm64<<<dim3(DM / 64, SEQ / 64), 256, 0, stream>>>(
        attn, w_out, d_out, SEQ, DM, DM, flagp, MODE_F32, MODE_FLAG, MODE_FLAG);
}

// Round 7
// 214.208 us; speedup vs baseline: 4.0146x; 4.0146x over previous
//
#include <hip/hip_runtime.h>
#include <hip/hip_bf16.h>

#define SEQ   2048
#define DM    1024
#define NH    16
#define DH    64
#define MAXD  128

typedef __attribute__((ext_vector_type(8))) short  short8;   // 8 bf16 = 4 VGPRs
typedef __attribute__((ext_vector_type(4))) float  float4v;  // MFMA 16x16 accumulator

__device__ __forceinline__ short8 ld8(const void* p) {
    short8 v; __builtin_memcpy(&v, p, 16); return v;
}
__device__ __forceinline__ void st8(void* p, short8 v) {
    __builtin_memcpy(p, &v, 16);
}
__device__ __forceinline__ short bf16bits(float f) {
    __hip_bfloat16 b = __float2bfloat16(f);
    short s; __builtin_memcpy(&s, &b, 2); return s;
}

// load 8 consecutive elements as bf16 bit-patterns
__device__ __forceinline__ short8 ld8bf(const __hip_bfloat16* p) { return ld8(p); }
__device__ __forceinline__ short8 ld8bf(const float* p) {
    float f[8]; __builtin_memcpy(f, p, 32);
    short8 v;
#pragma unroll
    for (int i = 0; i < 8; ++i) v[i] = bf16bits(f[i]);
    return v;
}

__device__ __forceinline__ __hip_bfloat16 tobf(float f) { return __float2bfloat16(f); }
__device__ __forceinline__ __hip_bfloat16 tobf(__hip_bfloat16 b) { return b; }

// ---------------------------------------------------------------------------
// Tiled transpose with bf16 output: dst[c][r] = bf16(src[r][c]).
// ---------------------------------------------------------------------------
template <typename TS>
__global__ __launch_bounds__(256) void transpose_to_bf16(
    const TS* __restrict__ src, __hip_bfloat16* __restrict__ dst,
    int s_stride, int d_stride) {
    __shared__ __hip_bfloat16 tile[32][33];
    const int t = threadIdx.x;
    const int tx = t % 32, ty = t / 32;           // ty 0..7
    const int c0 = blockIdx.x * 32, r0 = blockIdx.y * 32;
#pragma unroll
    for (int i = 0; i < 4; ++i)
        tile[ty + i * 8][tx] = tobf(src[(size_t)(r0 + ty + i * 8) * s_stride + c0 + tx]);
    __syncthreads();
#pragma unroll
    for (int i = 0; i < 4; ++i)
        dst[(size_t)(c0 + ty + i * 8) * d_stride + r0 + tx] = tile[tx][ty + i * 8];
}

// ---------------------------------------------------------------------------
// bf16 MFMA GEMM: C[M][N] = A[M][K] * BT[N][K]^T. 128x128x32 tiles, 4 waves.
// A fp32 or bf16 (staged to bf16 LDS); C fp32 or bf16.
// ---------------------------------------------------------------------------
template <typename TA, typename TC>
__global__ __launch_bounds__(256) void gemm_mfma(
    const TA* __restrict__ A,
    const __hip_bfloat16* __restrict__ BT,
    TC* __restrict__ C,
    int M, int N, int K) {
    __shared__ short As[128 * 40];   // [m][k], row stride 40 shorts (pad 8)
    __shared__ short Bs[128 * 40];   // [n][k]

    const int t = threadIdx.x;
    const int w = t >> 6, lane = t & 63;
    const int l15 = lane & 15, quad = lane >> 4;
    const int row0 = blockIdx.y * 128;
    const int col0 = blockIdx.x * 128;
    const int wm = w >> 1, wn = w & 1;

    float4v acc[4][4];
#pragma unroll
    for (int i = 0; i < 4; ++i)
#pragma unroll
        for (int j = 0; j < 4; ++j) acc[i][j] = (float4v){0.f, 0.f, 0.f, 0.f};

    for (int k0 = 0; k0 < K; k0 += 32) {
        // stage 128x32 A-tile and B-tile: 512 8-elem units each, 2 per thread
#pragma unroll
        for (int p = 0; p < 2; ++p) {
            const int idx = p * 256 + t;      // 0..511
            const int row = idx >> 2;         // 0..127
            const int u   = idx & 3;          // 8-elem unit within 32-elem row
            short8 av = ld8bf(A  + (size_t)(row0 + row) * K + k0 + u * 8);
            short8 bv = ld8bf(BT + (size_t)(col0 + row) * K + k0 + u * 8);
            st8(&As[row * 40 + u * 8], av);
            st8(&Bs[row * 40 + u * 8], bv);
        }
        __syncthreads();

        short8 af[4], bf[4];
#pragma unroll
        for (int mt = 0; mt < 4; ++mt)
            af[mt] = ld8(&As[(wm * 64 + mt * 16 + l15) * 40 + quad * 8]);
#pragma unroll
        for (int nt = 0; nt < 4; ++nt)
            bf[nt] = ld8(&Bs[(wn * 64 + nt * 16 + l15) * 40 + quad * 8]);
#pragma unroll
        for (int mt = 0; mt < 4; ++mt)
#pragma unroll
            for (int nt = 0; nt < 4; ++nt)
                acc[mt][nt] = __builtin_amdgcn_mfma_f32_16x16x32_bf16(
                    af[mt], bf[nt], acc[mt][nt], 0, 0, 0);
        __syncthreads();
    }

#pragma unroll
    for (int mt = 0; mt < 4; ++mt)
#pragma unroll
        for (int nt = 0; nt < 4; ++nt)
#pragma unroll
            for (int r = 0; r < 4; ++r) {
                const int row = row0 + wm * 64 + mt * 16 + quad * 4 + r;
                const int col = col0 + wn * 64 + nt * 16 + l15;
                float v = acc[mt][nt][r];
                if constexpr (__is_same(TC, float)) C[(size_t)row * N + col] = v;
                else C[(size_t)row * N + col] = __float2bfloat16(v);
            }
}

// ---------------------------------------------------------------------------
// MFMA flash attention with T5 relative bias.
// grid (SEQ/64, NH), 256 threads = 4 waves; wave w owns queries q0+w*16..+15.
// qkv bf16 [SEQ][3*DM]; vT bf16 [DM][SEQ]; rel_bias fp32 [MAXD][NH];
// out attnb bf16 [SEQ][DM].
// ---------------------------------------------------------------------------
__global__ __launch_bounds__(256) void attn_mfma(
    const __hip_bfloat16* __restrict__ qkv,
    const __hip_bfloat16* __restrict__ vT,
    const float* __restrict__ rel_bias,
    __hip_bfloat16* __restrict__ attnb) {
    __shared__ short Kt[64 * 72];        // [key][d]
    __shared__ short Vt[64 * 72];        // [d][key]
    __shared__ short Pl[4 * 16 * 72];    // per-wave P [q][key]
    __shared__ float biasL[MAXD];

    const int t = threadIdx.x;
    const int w = t >> 6, lane = t & 63;
    const int l15 = lane & 15, quad = lane >> 4;
    const int h  = blockIdx.y;
    const int q0 = blockIdx.x * 64;
    const int qw = q0 + w * 16;

    if (t < MAXD) biasL[t] = rel_bias[t * NH + h];

    // persistent Q fragments (A-layout): Q[q=l15][d = c*32 + quad*8 + j]
    short8 qf[2];
#pragma unroll
    for (int c = 0; c < 2; ++c)
        qf[c] = ld8(qkv + (size_t)(qw + l15) * (3 * DM) + h * DH + c * 32 + quad * 8);

    float4v o_acc[4];
#pragma unroll
    for (int nt = 0; nt < 4; ++nt) o_acc[nt] = (float4v){0.f, 0.f, 0.f, 0.f};
    float m_i[4], l_i[4];
#pragma unroll
    for (int r = 0; r < 4; ++r) { m_i[r] = -1e30f; l_i[r] = 0.f; }

    for (int k0 = 0; k0 < SEQ; k0 += 64) {
        // stage K tile [key][d] and V tile [d][key]: 512 16-B units each
#pragma unroll
        for (int p = 0; p < 2; ++p) {
            const int idx = p * 256 + t;      // 0..511
            const int row = idx >> 3;         // 0..63
            const int u   = idx & 7;          // 16-B unit within 128-B row
            short8 kv = ld8(qkv + (size_t)(k0 + row) * (3 * DM) + DM + h * DH + u * 8);
            short8 vv = ld8(vT + (size_t)(h * DH + row) * SEQ + k0 + u * 8);
            st8(&Kt[row * 72 + u * 8], kv);
            st8(&Vt[row * 72 + u * 8], vv);
        }
        __syncthreads();

        // S = Q K^T  (16q x 64keys per wave)
        float4v s_acc[4];
#pragma unroll
        for (int kt = 0; kt < 4; ++kt) s_acc[kt] = (float4v){0.f, 0.f, 0.f, 0.f};
#pragma unroll
        for (int c = 0; c < 2; ++c)
#pragma unroll
            for (int kt = 0; kt < 4; ++kt) {
                const int key = kt * 16 + l15;
                short8 kf = ld8(&Kt[key * 72 + (c * 4 + quad) * 8]);
                s_acc[kt] = __builtin_amdgcn_mfma_f32_16x16x32_bf16(qf[c], kf, s_acc[kt], 0, 0, 0);
            }

        // scale + relative bias
        float sv[4][4];
#pragma unroll
        for (int kt = 0; kt < 4; ++kt)
#pragma unroll
            for (int r = 0; r < 4; ++r) {
                const int kg = k0 + kt * 16 + l15;
                const int qg = qw + quad * 4 + r;
                int rel = kg - qg; if (rel < 0) rel = -rel;
                if (rel > MAXD - 1) rel = MAXD - 1;
                sv[kt][r] = s_acc[kt][r] * 0.125f + biasL[rel];
            }

        // online softmax (rows live across the 16 lanes of each quad)
        float rowm[4];
#pragma unroll
        for (int r = 0; r < 4; ++r)
            rowm[r] = fmaxf(fmaxf(sv[0][r], sv[1][r]), fmaxf(sv[2][r], sv[3][r]));
#pragma unroll
        for (int d = 1; d < 16; d <<= 1)
#pragma unroll
            for (int r = 0; r < 4; ++r) rowm[r] = fmaxf(rowm[r], __shfl_xor(rowm[r], d));

        float al[4], rs[4];
#pragma unroll
        for (int r = 0; r < 4; ++r) {
            const float mn = fmaxf(m_i[r], rowm[r]);
            al[r] = __expf(m_i[r] - mn);
            m_i[r] = mn;
            rs[r] = 0.f;
        }
#pragma unroll
        for (int kt = 0; kt < 4; ++kt)
#pragma unroll
            for (int r = 0; r < 4; ++r) {
                const float p = __expf(sv[kt][r] - m_i[r]);
                sv[kt][r] = p;
                rs[r] += p;
            }
#pragma unroll
        for (int d = 1; d < 16; d <<= 1)
#pragma unroll
            for (int r = 0; r < 4; ++r) rs[r] += __shfl_xor(rs[r], d);
#pragma unroll
        for (int r = 0; r < 4; ++r) l_i[r] = l_i[r] * al[r] + rs[r];
#pragma unroll
        for (int nt = 0; nt < 4; ++nt)
#pragma unroll
            for (int r = 0; r < 4; ++r) o_acc[nt][r] *= al[r];

        // P -> per-wave LDS ([q][key], stride 72): scalar short stores
#pragma unroll
        for (int kt = 0; kt < 4; ++kt)
#pragma unroll
            for (int r = 0; r < 4; ++r)
                Pl[w * 16 * 72 + (quad * 4 + r) * 72 + kt * 16 + l15] = bf16bits(sv[kt][r]);

        // O += P V   (A-frags from Pl, B-frags from Vt)
#pragma unroll
        for (int kc = 0; kc < 2; ++kc) {
            short8 pf = ld8(&Pl[w * 16 * 72 + l15 * 72 + kc * 32 + quad * 8]);
#pragma unroll
            for (int nt = 0; nt < 4; ++nt) {
                const int d = nt * 16 + l15;
                short8 vf = ld8(&Vt[d * 72 + (kc * 4 + quad) * 8]);
                o_acc[nt] = __builtin_amdgcn_mfma_f32_16x16x32_bf16(pf, vf, o_acc[nt], 0, 0, 0);
            }
        }
        __syncthreads();   // before next tile overwrites Kt/Vt
    }

    // normalize + store
#pragma unroll
    for (int nt = 0; nt < 4; ++nt)
#pragma unroll
        for (int r = 0; r < 4; ++r) {
            const int row = qw + quad * 4 + r;
            const int col = h * DH + nt * 16 + l15;
            attnb[(size_t)row * DM + col] = __float2bfloat16(o_acc[nt][r] / l_i[r]);
        }
}

extern "C" void kernel_launch(void* const* d_in, const int* in_sizes, int n_in,
                              void* d_out, int out_size, void* d_ws, size_t ws_size,
                              hipStream_t stream) {
    const float* x        = (const float*)d_in[0];   // [2048][1024] fp32
    const float* w_qkv    = (const float*)d_in[1];   // [1024][3072] fp32
    const float* w_out    = (const float*)d_in[2];   // [1024][1024] fp32
    const float* rel_bias = (const float*)d_in[3];   // [128][16]    fp32
    float* out = (float*)d_out;                      // [2048][1024] fp32

    // ws layout (16-B aligned): wqT 6MB | woT 2MB | qkvb 12MB | vT 4MB | attnb 4MB
    char* p = (char*)d_ws;
    __hip_bfloat16* wqT   = (__hip_bfloat16*)p;  p += (size_t)3 * DM * DM * 2;   // [3072][1024]
    __hip_bfloat16* woT   = (__hip_bfloat16*)p;  p += (size_t)DM * DM * 2;       // [1024][1024]
    __hip_bfloat16* qkvb  = (__hip_bfloat16*)p;  p += (size_t)SEQ * 3 * DM * 2;  // [2048][3072]
    __hip_bfloat16* vT    = (__hip_bfloat16*)p;  p += (size_t)DM * SEQ * 2;      // [1024][2048]
    __hip_bfloat16* attnb = (__hip_bfloat16*)p;                                  // [2048][1024]

    // weight transposes (fp32 -> bf16)
    transpose_to_bf16<float><<<dim3(3 * DM / 32, DM / 32), 256, 0, stream>>>(
        w_qkv, wqT, 3 * DM, DM);
    transpose_to_bf16<float><<<dim3(DM / 32, DM / 32), 256, 0, stream>>>(
        w_out, woT, DM, DM);

    // 1) qkv = x @ w_qkv   (fp32 A staged to bf16; bf16 out)
    gemm_mfma<float, __hip_bfloat16><<<dim3(3 * DM / 128, SEQ / 128), 256, 0, stream>>>(
        x, wqT, qkvb, SEQ, 3 * DM, DM);

    // V^T for attention B-frags (bf16 -> bf16)
    transpose_to_bf16<__hip_bfloat16><<<dim3(DM / 32, SEQ / 32), 256, 0, stream>>>(
        qkvb + 2 * DM, vT, 3 * DM, SEQ);

    // 2) attention
    attn_mfma<<<dim3(SEQ / 64, NH), 256, 0, stream>>>(qkvb, vT, rel_bias, attnb);

    // 3) out = attn @ w_out  (bf16 A; fp32 out)
    gemm_mfma<__hip_bfloat16, float><<<dim3(DM / 128, SEQ / 128), 256, 0, stream>>>(
        attnb, woT, out, SEQ, DM, DM);
}